// Round 7
// baseline (382.412 us; speedup 1.0000x reference)
//
#include <hip/hip_runtime.h>

typedef unsigned short u16;
typedef unsigned int u32;
using short8 = __attribute__((__ext_vector_type__(8))) short;
using f32x4  = __attribute__((__ext_vector_type__(4))) float;

#define DIM 768
#define QKV3 2304
#define SEQ 1024
#define SCALE 0.14433756729740643f  // 48^-0.5

// f32 -> bf16 RNE via compiler-native cast (emits the HW cvt; order-safe)
__device__ __forceinline__ u16 f2bf(float f) {
  __bf16 h = (__bf16)f;
  u16 r;
  __builtin_memcpy(&r, &h, 2);
  return r;
}
__device__ __forceinline__ u32 packbf(float lo, float hi) {
  return (u32)f2bf(lo) | ((u32)f2bf(hi) << 16);
}
__device__ __forceinline__ void store1(u16* p, float v) { *p = f2bf(v); }
__device__ __forceinline__ void store1(float* p, float v) { *p = v; }

__device__ __forceinline__ f32x4 mfma16(short8 a, short8 b, f32x4 c) {
  return __builtin_amdgcn_mfma_f32_16x16x32_bf16(a, b, c, 0, 0, 0);
}

// async 16B global -> LDS (wave-uniform base + lane*16; our mappings satisfy it)
__device__ __forceinline__ void gload16(const void* g, void* l) {
  __builtin_amdgcn_global_load_lds(
      (const __attribute__((address_space(1))) unsigned int*)g,
      (__attribute__((address_space(3))) unsigned int*)l, 16, 0, 0);
}

// ---------------- fp32 -> bf16 bulk convert (8 elems/thread) ----------------
__global__ __launch_bounds__(256)
void cvt_f32_bf16(const float* __restrict__ src, u16* __restrict__ dst, int n8) {
  int i = blockIdx.x * 256 + threadIdx.x;
  if (i < n8) {
    float4 a = ((const float4*)src)[2 * i];
    float4 b = ((const float4*)src)[2 * i + 1];
    uint4 o = {packbf(a.x, a.y), packbf(a.z, a.w), packbf(b.x, b.y), packbf(b.z, b.w)};
    ((uint4*)dst)[i] = o;
  }
}

// ---------------- MFMA GEMM: C[M][N] = A[M][K] @ W[N][K]^T + bias[N]
// Both operands bf16. m97-structure: global_load_lds staging (no VGPR
// round-trip), linear [128][32] LDS, 128x128 tile, BK=32, 4 waves.
// Frag indexing and epilogue mapping identical to the r1/r3-verified kernel.
template <typename TO>
__global__ __launch_bounds__(256, 4)
void gemm_bb(const u16* __restrict__ A, const u16* __restrict__ W,
             const float* __restrict__ bias, TO* __restrict__ C,
             int M, int N, int K) {
  __shared__ __align__(16) u16 As[128 * 32];  // [row][k] linear bf16
  __shared__ __align__(16) u16 Bs[128 * 32];
  const int tid = threadIdx.x;
  const int lane = tid & 63;
  const int wv = tid >> 6;
  const int lq = lane & 15;
  const int lc = lane >> 4;
  const int wm = wv >> 1, wn = wv & 1;
  const int row0 = blockIdx.y * 128, col0 = blockIdx.x * 128;

  f32x4 acc[4][4];
#pragma unroll
  for (int i = 0; i < 4; ++i)
#pragma unroll
    for (int j = 0; j < 4; ++j) acc[i][j] = (f32x4){0.f, 0.f, 0.f, 0.f};

#pragma unroll 1
  for (int k0 = 0; k0 < K; k0 += 32) {
    __syncthreads();  // LDS free (prev tile consumed)
#pragma unroll
    for (int i = 0; i < 2; ++i) {
      int c = i * 256 + tid;          // 16B chunk id; lds byte = c*16
      int r = c >> 2, kc = (c & 3) * 8;
      gload16(A + (size_t)(row0 + r) * K + k0 + kc, As + c * 8);
      gload16(W + (size_t)(col0 + r) * K + k0 + kc, Bs + c * 8);
    }
    __syncthreads();  // vmcnt(0) drained by barrier semantics -> tile ready
    short8 af[4], bf8[4];
#pragma unroll
    for (int i = 0; i < 4; ++i)
      af[i] = *(const short8*)(As + (wm * 64 + i * 16 + lq) * 32 + lc * 8);
#pragma unroll
    for (int j = 0; j < 4; ++j)
      bf8[j] = *(const short8*)(Bs + (wn * 64 + j * 16 + lq) * 32 + lc * 8);
#pragma unroll
    for (int i = 0; i < 4; ++i)
#pragma unroll
      for (int j = 0; j < 4; ++j)
        acc[i][j] = mfma16(af[i], bf8[j], acc[i][j]);  // C[row=lc*4+r][col=lq]
  }
#pragma unroll
  for (int j = 0; j < 4; ++j) {
    int col = col0 + wn * 64 + j * 16 + lq;
    float bv = bias[col];
#pragma unroll
    for (int i = 0; i < 4; ++i)
#pragma unroll
      for (int r = 0; r < 4; ++r) {
        int row = row0 + wm * 64 + i * 16 + lc * 4 + r;
        store1(C + (size_t)row * N + col, acc[i][j][r] + bv);
      }
  }
}

// ---------------- Fused talking-heads attention, all-MFMA, two-pass --------
// r6 schedule (dbuf pass 0, 3-barrier pass 1) + LDS-pipe cuts:
//  - mix2 operand-swapped: C[k][g2] -> W2 store = 2 uint2/thread (was 32 u16)
//  - sf/pf/kf[1] pad reads exec-masked (zero-A/B rows -> don't-care operands)
//  - P store as uint2
#define KS_ELEMS 24848
#define SMEM_ELEMS 80416
#define ATTN_SMEM 160832

__global__ __launch_bounds__(512, 2)
void attn_kernel(const u16* __restrict__ qkv,
                 const float* __restrict__ wl, const float* __restrict__ bl,
                 const float* __restrict__ ww, const float* __restrict__ bw,
                 u16* __restrict__ obuf) {
  extern __shared__ __align__(16) u16 smem[];
  u16* const Ks0 = smem;                 // [32 k][776] bf16
  u16* const Sb  = smem + KS_ELEMS;      // [32 q][776]: S/P at k*24+h, W2 at g2*40+k
  u16* const Vs  = smem + 2 * KS_ELEMS;  // pass0: Ks1 (2nd K buf); pass1: [768 d][40]

  const int tid = threadIdx.x;
  const int wv = tid >> 6;
  const int lane = tid & 63;
  const int lq = lane & 15;
  const int lc = lane >> 4;
  const int b = blockIdx.x >> 5;
  const int qt = blockIdx.x & 31;
  const size_t tokQ = (size_t)b * SEQ + (size_t)qt * 32;
  const size_t tokB = (size_t)b * SEQ;
  const int h0 = wv * 2;  // wave's head pair (QK) / g2 pair (PV)
  const short8 z8 = {0, 0, 0, 0, 0, 0, 0, 0};

  {  // zero ALL smem once (masked-frag stale regs & pads must be finite)
    u32* z = (u32*)smem;
    for (int i = tid; i < SMEM_ELEMS / 2; i += 512) z[i] = 0u;
  }

  // Q fragments: A[row=q(lq)][kd=d(lc*8+e)], d 48..63 zero
  short8 qf[2][2][2];  // [hh][qsub][dchunk]
#pragma unroll
  for (int hh = 0; hh < 2; ++hh)
#pragma unroll
    for (int qs = 0; qs < 2; ++qs) {
      const u16* qp = qkv + (tokQ + qs * 16 + lq) * QKV3 + (h0 + hh) * 48;
      qf[hh][qs][0] = *(const short8*)(qp + lc * 8);
      short8 zq = z8;
      if (lc < 2) zq = *(const short8*)(qp + 32 + lc * 8);
      qf[hh][qs][1] = zq;
    }

  // mix A-frags: wl' = wl*SCALE (scale folded), zero-padded h 16..31
  short8 wlF = z8;
  short8 wwF = z8;
  if (lc < 2) {
#pragma unroll
    for (int e = 0; e < 8; ++e) {
      wlF[e] = (short)f2bf(wl[lq * 16 + lc * 8 + e] * SCALE);
      wwF[e] = (short)f2bf(ww[lq * 16 + lc * 8 + e]);
    }
  }
  float blr[4];
#pragma unroll
  for (int r = 0; r < 4; ++r) blr[r] = bl[lc * 4 + r];
  const float bwq = bw[lq];  // mix2 bias: per-column (g2 = lq)

  // ---- staging machinery (global -> regs early; LDS write later)
  short8 kpre[6], vA[3], vB[3];
  auto issueK = [&](int kt) {
#pragma unroll
    for (int t = 0; t < 6; ++t) {
      int j = t * 512 + tid;
      int kr = j / 96, cc = j - kr * 96;
      kpre[t] = *(const short8*)(qkv + (tokB + (size_t)kt * 32 + kr) * QKV3 + DIM + cc * 8);
    }
  };
  auto issueV = [&](int kt) {
#pragma unroll
    for (int t = 0; t < 3; ++t) {
      int cc = (tid >> 4) + t * 32;
      int kk = tid & 15;
      const u16* v0 = qkv + (tokB + (size_t)kt * 32 + 2 * kk) * QKV3 + 2 * DIM + cc * 8;
      vA[t] = *(const short8*)v0;
      vB[t] = *(const short8*)(v0 + QKV3);
    }
  };
  auto writeK = [&](u16* dst) {
#pragma unroll
    for (int t = 0; t < 6; ++t) {
      int j = t * 512 + tid;
      int kr = j / 96, cc = j - kr * 96;
      *(short8*)(dst + kr * 776 + cc * 8) = kpre[t];
    }
  };
  auto writeV = [&]() {
#pragma unroll
    for (int t = 0; t < 3; ++t) {
      int cc = (tid >> 4) + t * 32;
      int kk = tid & 15;
#pragma unroll
      for (int e = 0; e < 8; ++e)
        *(u32*)(Vs + (cc * 8 + e) * 40 + 2 * kk) =
            (u32)(u16)vA[t][e] | ((u32)(u16)vB[t][e] << 16);
    }
  };
  auto doQK = [&](const u16* kbase) {  // K LDS -> frags -> S (bf16) in Sb
#pragma unroll
    for (int ks = 0; ks < 2; ++ks) {
      short8 kf[2][2];
#pragma unroll
      for (int hh = 0; hh < 2; ++hh) {
        const u16* kb = kbase + (ks * 16 + lq) * 776 + (h0 + hh) * 48;
        kf[hh][0] = *(const short8*)(kb + lc * 8);
        short8 k1 = z8;
        if (lc < 2) k1 = *(const short8*)(kb + 32 + lc * 8);  // d32..47
        kf[hh][1] = k1;
      }
#pragma unroll
      for (int qs = 0; qs < 2; ++qs) {
        f32x4 s0 = {0.f, 0.f, 0.f, 0.f}, s1 = {0.f, 0.f, 0.f, 0.f};
        s0 = mfma16(qf[0][qs][0], kf[0][0], s0);
        s0 = mfma16(qf[0][qs][1], kf[0][1], s0);
        s1 = mfma16(qf[1][qs][0], kf[1][0], s1);
        s1 = mfma16(qf[1][qs][1], kf[1][1], s1);
#pragma unroll
        for (int r = 0; r < 4; ++r) {
          int q = qs * 16 + lc * 4 + r;
          int k = ks * 16 + lq;
          *(u32*)(Sb + q * 776 + k * 24 + h0) = packbf(s0[r], s1[r]);
        }
      }
    }
  };
  auto doPV = [&](f32x4 O[2][3][2]) {
#pragma unroll
    for (int hh = 0; hh < 2; ++hh) {
      const int g2 = h0 + hh;
      short8 w2f[2];
#pragma unroll
      for (int qs = 0; qs < 2; ++qs)
        w2f[qs] = *(const short8*)(Sb + (qs * 16 + lq) * 776 + g2 * 40 + lc * 8);
#pragma unroll
      for (int dt = 0; dt < 3; ++dt) {
        short8 vf = *(const short8*)(Vs + (g2 * 48 + dt * 16 + lq) * 40 + lc * 8);
#pragma unroll
        for (int qs = 0; qs < 2; ++qs)
          O[hh][dt][qs] = mfma16(w2f[qs], vf, O[hh][dt][qs]);  // C[q=lc*4+r][d=lq]
      }
    }
  };

  float Zac[4][4], invZ[4][4];
#pragma unroll
  for (int i = 0; i < 4; ++i)
#pragma unroll
    for (int r = 0; r < 4; ++r) Zac[i][r] = 0.f;

  f32x4 O[2][3][2];  // [hh][dtile][qsub]
#pragma unroll
  for (int hh = 0; hh < 2; ++hh)
#pragma unroll
    for (int dt = 0; dt < 3; ++dt)
#pragma unroll
      for (int qs = 0; qs < 2; ++qs) O[hh][dt][qs] = (f32x4){0.f, 0.f, 0.f, 0.f};

  // ================= pass 0: softmax denominators (K double-buffered) ======
  issueK(0);
  __syncthreads();   // zero-fill visible
  writeK(Ks0);       // stage tile 0
  issueK(1);
  __syncthreads();   // tile 0 ready
#pragma unroll 1
  for (int kt = 0; kt < 32; ++kt) {
    u16* cur = (kt & 1) ? Vs : Ks0;
    u16* nxt = (kt & 1) ? Ks0 : Vs;
    if (kt < 31) {
      writeK(nxt);                       // stage kt+1 (regs from 2 iters back)
      issueK(kt == 30 ? 0 : kt + 2);     // kt=30 prefetches tile 0 for pass 1
    }
    doQK(cur);
    __syncthreads();  // (1) Sb visible cross-wave; nxt staged
#pragma unroll
    for (int i = 0; i < 4; ++i) {
      const int q = wv * 4 + i;
      const u16* sq = Sb + q * 776;
#pragma unroll
      for (int ks = 0; ks < 2; ++ks) {
        short8 sf = z8;
        if (lc < 2) sf = *(const short8*)(sq + (ks * 16 + lq) * 24 + lc * 8);
        f32x4 cin = {blr[0], blr[1], blr[2], blr[3]};
        f32x4 L = mfma16(wlF, sf, cin);  // L[g=lc*4+r][k=ks*16+lq]
#pragma unroll
        for (int r = 0; r < 4; ++r) Zac[i][r] += __expf(L[r]);
      }
    }
    __syncthreads();  // (2) Sb free for next doQK; cur free for re-stage
  }
  issueV(0);  // V prefetch for pass 1 (latency hidden under Z reduction)
  // reduce Z over the 16 k-lanes
#pragma unroll
  for (int i = 0; i < 4; ++i)
#pragma unroll
    for (int r = 0; r < 4; ++r) {
      float z = Zac[i][r];
      z += __shfl_xor(z, 1);
      z += __shfl_xor(z, 2);
      z += __shfl_xor(z, 4);
      z += __shfl_xor(z, 8);
      invZ[i][r] = 1.0f / z;
    }

  // ================= pass 1: P, W2, O (3 barriers/kt) =================
#pragma unroll 1
  for (int kt = 0; kt < 32; ++kt) {
    if (kt) doPV(O);    // PV(kt-1): reads Vs + W2 (disjoint from writeK below)
    writeK(Ks0);        // stage K(kt); regs from prev iter (kt=0: pass-0 tail)
    __syncthreads();    // s1: K staged; PV done (Vs/Sb S-slots now free)
    writeV();           // stage V(kt)
    doQK(Ks0);          // S(kt) -> Sb (overwrites W2(kt-1), PV done)
    if (kt < 31) { issueK(kt + 1); issueV(kt + 1); }
    __syncthreads();    // s2: Vs + S visible
#pragma unroll
    for (int i = 0; i < 4; ++i) {
      const int q = wv * 4 + i;
      u16* const sq = Sb + q * 776;
      f32x4 L[2];
#pragma unroll
      for (int ks = 0; ks < 2; ++ks) {
        short8 sf = z8;
        if (lc < 2) sf = *(const short8*)(sq + (ks * 16 + lq) * 24 + lc * 8);
        f32x4 cin = {blr[0], blr[1], blr[2], blr[3]};
        L[ks] = mfma16(wlF, sf, cin);
      }
#pragma unroll
      for (int ks = 0; ks < 2; ++ks) {
        float p0 = __expf(L[ks][0]) * invZ[i][0];
        float p1 = __expf(L[ks][1]) * invZ[i][1];
        float p2 = __expf(L[ks][2]) * invZ[i][2];
        float p3 = __expf(L[ks][3]) * invZ[i][3];
        uint2 pv = {packbf(p0, p1), packbf(p2, p3)};
        *(uint2*)(sq + (ks * 16 + lq) * 24 + lc * 4) = pv;
      }
      // mix2 SWAPPED: C[k=ks*16+lc*4+r][g2=lq]; cin = bw[g2=lq]
      f32x4 W2[2];
      f32x4 cw = {bwq, bwq, bwq, bwq};
#pragma unroll
      for (int ks = 0; ks < 2; ++ks) {
        short8 pf = z8;
        if (lc < 2) pf = *(const short8*)(sq + (ks * 16 + lq) * 24 + lc * 8);
        W2[ks] = mfma16(pf, wwF, cw);
      }
#pragma unroll
      for (int ks = 0; ks < 2; ++ks) {
        uint2 wv2 = {packbf(W2[ks][0], W2[ks][1]), packbf(W2[ks][2], W2[ks][3])};
        *(uint2*)(sq + lq * 40 + ks * 16 + lc * 4) = wv2;  // [g2=lq][k contig]
      }
    }
    __syncthreads();    // s3: W2 visible to all waves
  }
  doPV(O);  // PV(31)

  // write O: row (b,q), col = g2*48 + dt*16 + lq  (r1/r3 verified mapping)
#pragma unroll
  for (int hh = 0; hh < 2; ++hh)
#pragma unroll
    for (int dt = 0; dt < 3; ++dt)
#pragma unroll
      for (int qs = 0; qs < 2; ++qs)
#pragma unroll
        for (int r = 0; r < 4; ++r) {
          size_t row = tokQ + qs * 16 + lc * 4 + r;
          int col = (h0 + hh) * 48 + dt * 16 + lq;
          obuf[row * DIM + col] = f2bf(O[hh][dt][qs][r]);
        }
}

extern "C" void kernel_launch(void* const* d_in, const int* in_sizes, int n_in,
                              void* d_out, int out_size, void* d_ws, size_t ws_size,
                              hipStream_t stream) {
  const float* x      = (const float*)d_in[0];
  const float* w_qkv  = (const float*)d_in[1];
  const float* b_qkv  = (const float*)d_in[2];
  const float* w_l    = (const float*)d_in[3];
  const float* b_l    = (const float*)d_in[4];
  const float* w_w    = (const float*)d_in[5];
  const float* b_w    = (const float*)d_in[6];
  const float* w_proj = (const float*)d_in[7];
  const float* b_proj = (const float*)d_in[8];
  float* out = (float*)d_out;

  u16* qkv_buf  = (u16*)d_ws;                     // [8192][2304] bf16
  u16* attn_buf = qkv_buf + (size_t)8192 * QKV3;  // [8192][768]  bf16
  u16* x_bf     = attn_buf;       // alias: free until attn_kernel writes it
  // scratch homes for pre-converted weights (both in otherwise-dead regions):
  u16* w_qkv_bf  = (u16*)d_out;   // out is written only by the final GEMM
  u16* w_proj_bf = qkv_buf;       // qkv_buf is dead after attn_kernel

  static int attr_done = 0;
  if (!attr_done) {
    (void)hipFuncSetAttribute(reinterpret_cast<const void*>(attn_kernel),
                              hipFuncAttributeMaxDynamicSharedMemorySize,
                              ATTN_SMEM);
    attr_done = 1;
  }

  // 0) weight + activation fp32 -> bf16
  cvt_f32_bf16<<<dim3(864), 256, 0, stream>>>(w_qkv, w_qkv_bf, 221184);
  cvt_f32_bf16<<<dim3(3072), 256, 0, stream>>>(x, x_bf, 786432);
  // 1) QKV projection: bf16 x bf16 -> bf16
  gemm_bb<u16><<<dim3(QKV3 / 128, 8192 / 128), 256, 0, stream>>>(
      x_bf, w_qkv_bf, b_qkv, qkv_buf, 8192, QKV3, DIM);
  // 2) fused talking-heads attention
  attn_kernel<<<dim3(8 * 32), dim3(512), ATTN_SMEM, stream>>>(
      qkv_buf, w_l, b_l, w_w, b_w, attn_buf);
  // 3) output projection: bf16 x bf16 -> fp32 (w_proj converted into dead qkv_buf)
  cvt_f32_bf16<<<dim3(288), 256, 0, stream>>>(w_proj, w_proj_bf, 73728);
  gemm_bb<float><<<dim3(DIM / 128, 8192 / 128), 256, 0, stream>>>(
      attn_buf, w_proj_bf, b_proj, out, 8192, DIM, DIM);
}

// Round 9
// 356.649 us; speedup vs baseline: 1.0722x; 1.0722x over previous
//
#include <hip/hip_runtime.h>

typedef unsigned short u16;
typedef unsigned int u32;
using short8 = __attribute__((__ext_vector_type__(8))) short;
using f32x4  = __attribute__((__ext_vector_type__(4))) float;

#define DIM 768
#define QKV3 2304
#define SEQ 1024
#define SCALE 0.14433756729740643f  // 48^-0.5

// f32 -> bf16 RNE via compiler-native cast (emits the HW cvt; order-safe)
__device__ __forceinline__ u16 f2bf(float f) {
  __bf16 h = (__bf16)f;
  u16 r;
  __builtin_memcpy(&r, &h, 2);
  return r;
}
__device__ __forceinline__ u32 packbf(float lo, float hi) {
  return (u32)f2bf(lo) | ((u32)f2bf(hi) << 16);
}
__device__ __forceinline__ void store1(u16* p, float v) { *p = f2bf(v); }
__device__ __forceinline__ void store1(float* p, float v) { *p = v; }

__device__ __forceinline__ f32x4 mfma16(short8 a, short8 b, f32x4 c) {
  return __builtin_amdgcn_mfma_f32_16x16x32_bf16(a, b, c, 0, 0, 0);
}

// async 16B global -> LDS (LDS dest = wave-uniform base + lane*16)
__device__ __forceinline__ void gload16(const void* g, void* l) {
  __builtin_amdgcn_global_load_lds(
      (const __attribute__((address_space(1))) unsigned int*)g,
      (__attribute__((address_space(3))) unsigned int*)l, 16, 0, 0);
}

// ---------------- fp32 -> bf16 bulk convert (8 elems/thread) ----------------
__global__ __launch_bounds__(256)
void cvt_f32_bf16(const float* __restrict__ src, u16* __restrict__ dst, int n8) {
  int i = blockIdx.x * 256 + threadIdx.x;
  if (i < n8) {
    float4 a = ((const float4*)src)[2 * i];
    float4 b = ((const float4*)src)[2 * i + 1];
    uint4 o = {packbf(a.x, a.y), packbf(a.z, a.w), packbf(b.x, b.y), packbf(b.z, b.w)};
    ((uint4*)dst)[i] = o;
  }
}

// ---------------- MFMA GEMM: C[M][N] = A[M][K] @ W[N][K]^T + bias[N]
// Both operands bf16. global_load_lds staging with PRE-SWIZZLED SOURCE
// (rule #21: linear LDS dest + kc^=row&7 on source + same XOR on read) so
// frag ds_read_b128 is ~2-way instead of 8/16-way. BK=64, 4 blocks/CU.
// Frag indexing and epilogue mapping identical to the r1/r3-verified kernel.
template <typename TO>
__global__ __launch_bounds__(256, 4)
void gemm_bb(const u16* __restrict__ A, const u16* __restrict__ W,
             const float* __restrict__ bias, TO* __restrict__ C,
             int M, int N, int K) {
  __shared__ __align__(16) u16 As[128 * 64];  // [row][k] linear, src-swizzled
  __shared__ __align__(16) u16 Bs[128 * 64];
  const int tid = threadIdx.x;
  const int lane = tid & 63;
  const int wv = tid >> 6;
  const int lq = lane & 15;
  const int lc = lane >> 4;
  const int wm = wv >> 1, wn = wv & 1;
  const int row0 = blockIdx.y * 128, col0 = blockIdx.x * 128;

  f32x4 acc[4][4];
#pragma unroll
  for (int i = 0; i < 4; ++i)
#pragma unroll
    for (int j = 0; j < 4; ++j) acc[i][j] = (f32x4){0.f, 0.f, 0.f, 0.f};

#pragma unroll 1
  for (int k0 = 0; k0 < K; k0 += 64) {
    __syncthreads();  // LDS free (prev tile consumed)
#pragma unroll
    for (int i = 0; i < 4; ++i) {
      int c = i * 256 + tid;              // 16B chunk id; lds byte = c*16
      int r = c >> 3;                     // 8 chunks per 64-elem row
      int kc = ((c & 7) ^ (r & 7)) * 8;   // pre-swizzled source chunk
      gload16(A + (size_t)(row0 + r) * K + k0 + kc, As + c * 8);
      gload16(W + (size_t)(col0 + r) * K + k0 + kc, Bs + c * 8);
    }
    __syncthreads();  // barrier drains vmcnt -> tile ready
#pragma unroll
    for (int kk = 0; kk < 2; ++kk) {
      short8 af[4], bf8[4];
#pragma unroll
      for (int i = 0; i < 4; ++i) {
        int R = wm * 64 + i * 16 + lq;
        af[i] = *(const short8*)(As + R * 64 + (((kk * 4 + lc) ^ (R & 7)) * 8));
      }
#pragma unroll
      for (int j = 0; j < 4; ++j) {
        int R = wn * 64 + j * 16 + lq;
        bf8[j] = *(const short8*)(Bs + R * 64 + (((kk * 4 + lc) ^ (R & 7)) * 8));
      }
#pragma unroll
      for (int i = 0; i < 4; ++i)
#pragma unroll
        for (int j = 0; j < 4; ++j)
          acc[i][j] = mfma16(af[i], bf8[j], acc[i][j]);  // C[row=lc*4+r][col=lq]
    }
  }
#pragma unroll
  for (int j = 0; j < 4; ++j) {
    int col = col0 + wn * 64 + j * 16 + lq;
    float bv = bias[col];
#pragma unroll
    for (int i = 0; i < 4; ++i)
#pragma unroll
      for (int r = 0; r < 4; ++r) {
        int row = row0 + wm * 64 + i * 16 + lc * 4 + r;
        store1(C + (size_t)row * N + col, acc[i][j][r] + bv);
      }
  }
}

// ---------------- Fused talking-heads attention, all-MFMA, two-pass --------
// r6 schedule (dbuf pass 0, 3-barrier pass 1). Deltas vs r6 (all using the
// r7-verified operand-swap convention; NO exec-masked fragment reads):
//  - mix2 swapped: C[k][g2] -> W2 store = 2 uint2/thread
//  - P store as uint2
//  - PV swapped: O^T frags (lane holds 4 consecutive d for q=lq) -> uint2 epilogue
#define KS_ELEMS 24848
#define SMEM_ELEMS 80416
#define ATTN_SMEM 160832

__global__ __launch_bounds__(512, 2)
void attn_kernel(const u16* __restrict__ qkv,
                 const float* __restrict__ wl, const float* __restrict__ bl,
                 const float* __restrict__ ww, const float* __restrict__ bw,
                 u16* __restrict__ obuf) {
  extern __shared__ __align__(16) u16 smem[];
  u16* const Ks0 = smem;                 // [32 k][776] bf16
  u16* const Sb  = smem + KS_ELEMS;      // [32 q][776]: S/P at k*24+h, W2 at g2*40+k
  u16* const Vs  = smem + 2 * KS_ELEMS;  // pass0: Ks1 (2nd K buf); pass1: [768 d][40]

  const int tid = threadIdx.x;
  const int wv = tid >> 6;
  const int lane = tid & 63;
  const int lq = lane & 15;
  const int lc = lane >> 4;
  const int b = blockIdx.x >> 5;
  const int qt = blockIdx.x & 31;
  const size_t tokQ = (size_t)b * SEQ + (size_t)qt * 32;
  const size_t tokB = (size_t)b * SEQ;
  const int h0 = wv * 2;  // wave's head pair (QK) / g2 pair (PV)

  {  // zero ALL smem once (pad slots are MFMA-read as don't-care; must be finite)
    u32* z = (u32*)smem;
    for (int i = tid; i < SMEM_ELEMS / 2; i += 512) z[i] = 0u;
  }

  // Q fragments: A[row=q(lq)][kd=d(lc*8+e)], d 48..63 MUST be zero (B-side
  // there holds the next head's real K data)
  short8 qf[2][2][2];  // [hh][qsub][dchunk]
#pragma unroll
  for (int hh = 0; hh < 2; ++hh)
#pragma unroll
    for (int qs = 0; qs < 2; ++qs) {
      const u16* qp = qkv + (tokQ + qs * 16 + lq) * QKV3 + (h0 + hh) * 48;
      qf[hh][qs][0] = *(const short8*)(qp + lc * 8);
      short8 zq = {0, 0, 0, 0, 0, 0, 0, 0};
      if (lc < 2) zq = *(const short8*)(qp + 32 + lc * 8);
      qf[hh][qs][1] = zq;
    }

  // mix A-frags: wl' = wl*SCALE (scale folded), zero-padded h 16..31
  short8 wlF = {0, 0, 0, 0, 0, 0, 0, 0};
  short8 wwF = {0, 0, 0, 0, 0, 0, 0, 0};
  if (lc < 2) {
#pragma unroll
    for (int e = 0; e < 8; ++e) {
      wlF[e] = (short)f2bf(wl[lq * 16 + lc * 8 + e] * SCALE);
      wwF[e] = (short)f2bf(ww[lq * 16 + lc * 8 + e]);
    }
  }
  float blr[4];
#pragma unroll
  for (int r = 0; r < 4; ++r) blr[r] = bl[lc * 4 + r];
  const float bwq = bw[lq];  // mix2 bias: per-column (g2 = lq)

  // ---- staging machinery (global -> regs early; LDS write later)
  short8 kpre[6], vA[3], vB[3];
  auto issueK = [&](int kt) {
#pragma unroll
    for (int t = 0; t < 6; ++t) {
      int j = t * 512 + tid;
      int kr = j / 96, cc = j - kr * 96;
      kpre[t] = *(const short8*)(qkv + (tokB + (size_t)kt * 32 + kr) * QKV3 + DIM + cc * 8);
    }
  };
  auto issueV = [&](int kt) {
#pragma unroll
    for (int t = 0; t < 3; ++t) {
      int cc = (tid >> 4) + t * 32;
      int kk = tid & 15;
      const u16* v0 = qkv + (tokB + (size_t)kt * 32 + 2 * kk) * QKV3 + 2 * DIM + cc * 8;
      vA[t] = *(const short8*)v0;
      vB[t] = *(const short8*)(v0 + QKV3);
    }
  };
  auto writeK = [&](u16* dst) {
#pragma unroll
    for (int t = 0; t < 6; ++t) {
      int j = t * 512 + tid;
      int kr = j / 96, cc = j - kr * 96;
      *(short8*)(dst + kr * 776 + cc * 8) = kpre[t];
    }
  };
  auto writeV = [&]() {
#pragma unroll
    for (int t = 0; t < 3; ++t) {
      int cc = (tid >> 4) + t * 32;
      int kk = tid & 15;
#pragma unroll
      for (int e = 0; e < 8; ++e)
        *(u32*)(Vs + (cc * 8 + e) * 40 + 2 * kk) =
            (u32)(u16)vA[t][e] | ((u32)(u16)vB[t][e] << 16);
    }
  };
  auto doQK = [&](const u16* kbase) {  // K LDS -> frags -> S (bf16) in Sb
#pragma unroll
    for (int ks = 0; ks < 2; ++ks) {
      short8 kf[2][2];
#pragma unroll
      for (int hh = 0; hh < 2; ++hh) {
        const u16* kb = kbase + (ks * 16 + lq) * 776 + (h0 + hh) * 48;
        kf[hh][0] = *(const short8*)(kb + lc * 8);
        kf[hh][1] = *(const short8*)(kb + 32 + lc * 8);  // tail dont-care (A=0)
      }
#pragma unroll
      for (int qs = 0; qs < 2; ++qs) {
        f32x4 s0 = {0.f, 0.f, 0.f, 0.f}, s1 = {0.f, 0.f, 0.f, 0.f};
        s0 = mfma16(qf[0][qs][0], kf[0][0], s0);
        s0 = mfma16(qf[0][qs][1], kf[0][1], s0);
        s1 = mfma16(qf[1][qs][0], kf[1][0], s1);
        s1 = mfma16(qf[1][qs][1], kf[1][1], s1);
#pragma unroll
        for (int r = 0; r < 4; ++r) {
          int q = qs * 16 + lc * 4 + r;
          int k = ks * 16 + lq;
          *(u32*)(Sb + q * 776 + k * 24 + h0) = packbf(s0[r], s1[r]);
        }
      }
    }
  };
  auto doPV = [&](f32x4 O[2][3][2]) {
    // SWAPPED: O^T[d][q] = V^T frags (A) x W2 frags (B); C[d=lc*4+r][q=lq]
#pragma unroll
    for (int hh = 0; hh < 2; ++hh) {
      const int g2 = h0 + hh;
      short8 w2f[2];
#pragma unroll
      for (int qs = 0; qs < 2; ++qs)
        w2f[qs] = *(const short8*)(Sb + (qs * 16 + lq) * 776 + g2 * 40 + lc * 8);
#pragma unroll
      for (int dt = 0; dt < 3; ++dt) {
        short8 vf = *(const short8*)(Vs + (g2 * 48 + dt * 16 + lq) * 40 + lc * 8);
#pragma unroll
        for (int qs = 0; qs < 2; ++qs)
          O[hh][dt][qs] = mfma16(vf, w2f[qs], O[hh][dt][qs]);
      }
    }
  };

  float Zac[4][4], invZ[4][4];
#pragma unroll
  for (int i = 0; i < 4; ++i)
#pragma unroll
    for (int r = 0; r < 4; ++r) Zac[i][r] = 0.f;

  f32x4 O[2][3][2];  // [hh][dtile][qsub]  (O^T fragments)
#pragma unroll
  for (int hh = 0; hh < 2; ++hh)
#pragma unroll
    for (int dt = 0; dt < 3; ++dt)
#pragma unroll
      for (int qs = 0; qs < 2; ++qs) O[hh][dt][qs] = (f32x4){0.f, 0.f, 0.f, 0.f};

  // ================= pass 0: softmax denominators (K double-buffered) ======
  issueK(0);
  __syncthreads();   // zero-fill visible
  writeK(Ks0);       // stage tile 0
  issueK(1);
  __syncthreads();   // tile 0 ready
#pragma unroll 1
  for (int kt = 0; kt < 32; ++kt) {
    u16* cur = (kt & 1) ? Vs : Ks0;
    u16* nxt = (kt & 1) ? Ks0 : Vs;
    if (kt < 31) {
      writeK(nxt);                       // stage kt+1 (regs from 2 iters back)
      issueK(kt == 30 ? 0 : kt + 2);     // kt=30 prefetches tile 0 for pass 1
    }
    doQK(cur);
    __syncthreads();  // (1) Sb visible cross-wave; nxt staged
#pragma unroll
    for (int i = 0; i < 4; ++i) {
      const int q = wv * 4 + i;
      const u16* sq = Sb + q * 776;
#pragma unroll
      for (int ks = 0; ks < 2; ++ks) {
        short8 sf = *(const short8*)(sq + (ks * 16 + lq) * 24 + lc * 8);
        f32x4 cin = {blr[0], blr[1], blr[2], blr[3]};
        f32x4 L = mfma16(wlF, sf, cin);  // L[g=lc*4+r][k=ks*16+lq]
#pragma unroll
        for (int r = 0; r < 4; ++r) Zac[i][r] += __expf(L[r]);
      }
    }
    __syncthreads();  // (2) Sb free for next doQK; cur free for re-stage
  }
  issueV(0);  // V prefetch for pass 1 (latency hidden under Z reduction)
  // reduce Z over the 16 k-lanes
#pragma unroll
  for (int i = 0; i < 4; ++i)
#pragma unroll
    for (int r = 0; r < 4; ++r) {
      float z = Zac[i][r];
      z += __shfl_xor(z, 1);
      z += __shfl_xor(z, 2);
      z += __shfl_xor(z, 4);
      z += __shfl_xor(z, 8);
      invZ[i][r] = 1.0f / z;
    }

  // ================= pass 1: P, W2, O (3 barriers/kt) =================
#pragma unroll 1
  for (int kt = 0; kt < 32; ++kt) {
    if (kt) doPV(O);    // PV(kt-1): reads Vs + W2 (disjoint from writeK below)
    writeK(Ks0);        // stage K(kt); regs from prev iter (kt=0: pass-0 tail)
    __syncthreads();    // s1: K staged; PV done (Vs/Sb S-slots now free)
    writeV();           // stage V(kt)
    doQK(Ks0);          // S(kt) -> Sb (overwrites W2(kt-1), PV done)
    if (kt < 31) { issueK(kt + 1); issueV(kt + 1); }
    __syncthreads();    // s2: Vs + S visible
#pragma unroll
    for (int i = 0; i < 4; ++i) {
      const int q = wv * 4 + i;
      u16* const sq = Sb + q * 776;
      f32x4 L[2];
#pragma unroll
      for (int ks = 0; ks < 2; ++ks) {
        short8 sf = *(const short8*)(sq + (ks * 16 + lq) * 24 + lc * 8);
        f32x4 cin = {blr[0], blr[1], blr[2], blr[3]};
        L[ks] = mfma16(wlF, sf, cin);
      }
#pragma unroll
      for (int ks = 0; ks < 2; ++ks) {
        float p0 = __expf(L[ks][0]) * invZ[i][0];
        float p1 = __expf(L[ks][1]) * invZ[i][1];
        float p2 = __expf(L[ks][2]) * invZ[i][2];
        float p3 = __expf(L[ks][3]) * invZ[i][3];
        uint2 pv = {packbf(p0, p1), packbf(p2, p3)};
        *(uint2*)(sq + (ks * 16 + lq) * 24 + lc * 4) = pv;
      }
      // mix2 SWAPPED (r7-verified): C[k=ks*16+lc*4+r][g2=lq]; cin = bw[lq]
      f32x4 W2[2];
      f32x4 cw = {bwq, bwq, bwq, bwq};
#pragma unroll
      for (int ks = 0; ks < 2; ++ks) {
        short8 pf = *(const short8*)(sq + (ks * 16 + lq) * 24 + lc * 8);
        W2[ks] = mfma16(pf, wwF, cw);
      }
#pragma unroll
      for (int ks = 0; ks < 2; ++ks) {
        uint2 wv2 = {packbf(W2[ks][0], W2[ks][1]), packbf(W2[ks][2], W2[ks][3])};
        *(uint2*)(sq + lq * 40 + ks * 16 + lc * 4) = wv2;  // [g2=lq][k contig]
      }
    }
    __syncthreads();    // s3: W2 visible to all waves
  }
  doPV(O);  // PV(31)

  // write O^T frags: row (b, q=lq), 4 consecutive d per uint2 store
#pragma unroll
  for (int hh = 0; hh < 2; ++hh)
#pragma unroll
    for (int dt = 0; dt < 3; ++dt)
#pragma unroll
      for (int qs = 0; qs < 2; ++qs) {
        size_t row = tokQ + qs * 16 + lq;
        int col = (h0 + hh) * 48 + dt * 16 + lc * 4;
        uint2 p = {packbf(O[hh][dt][qs][0], O[hh][dt][qs][1]),
                   packbf(O[hh][dt][qs][2], O[hh][dt][qs][3])};
        *(uint2*)(obuf + row * DIM + col) = p;
      }
}

extern "C" void kernel_launch(void* const* d_in, const int* in_sizes, int n_in,
                              void* d_out, int out_size, void* d_ws, size_t ws_size,
                              hipStream_t stream) {
  const float* x      = (const float*)d_in[0];
  const float* w_qkv  = (const float*)d_in[1];
  const float* b_qkv  = (const float*)d_in[2];
  const float* w_l    = (const float*)d_in[3];
  const float* b_l    = (const float*)d_in[4];
  const float* w_w    = (const float*)d_in[5];
  const float* b_w    = (const float*)d_in[6];
  const float* w_proj = (const float*)d_in[7];
  const float* b_proj = (const float*)d_in[8];
  float* out = (float*)d_out;

  u16* qkv_buf  = (u16*)d_ws;                     // [8192][2304] bf16
  u16* attn_buf = qkv_buf + (size_t)8192 * QKV3;  // [8192][768]  bf16
  u16* x_bf     = attn_buf;       // alias: free until attn_kernel writes it
  // scratch homes for pre-converted weights (both in otherwise-dead regions):
  u16* w_qkv_bf  = (u16*)d_out;   // out is written only by the final GEMM
  u16* w_proj_bf = qkv_buf;       // qkv_buf is dead after attn_kernel

  static int attr_done = 0;
  if (!attr_done) {
    (void)hipFuncSetAttribute(reinterpret_cast<const void*>(attn_kernel),
                              hipFuncAttributeMaxDynamicSharedMemorySize,
                              ATTN_SMEM);
    attr_done = 1;
  }

  // 0) weight + activation fp32 -> bf16
  cvt_f32_bf16<<<dim3(864), 256, 0, stream>>>(w_qkv, w_qkv_bf, 221184);
  cvt_f32_bf16<<<dim3(3072), 256, 0, stream>>>(x, x_bf, 786432);
  // 1) QKV projection: bf16 x bf16 -> bf16
  gemm_bb<u16><<<dim3(QKV3 / 128, 8192 / 128), 256, 0, stream>>>(
      x_bf, w_qkv_bf, b_qkv, qkv_buf, 8192, QKV3, DIM);
  // 2) fused talking-heads attention
  attn_kernel<<<dim3(8 * 32), dim3(512), ATTN_SMEM, stream>>>(
      qkv_buf, w_l, b_l, w_w, b_w, attn_buf);
  // 3) output projection: bf16 x bf16 -> fp32 (w_proj converted into dead qkv_buf)
  cvt_f32_bf16<<<dim3(288), 256, 0, stream>>>(w_proj, w_proj_bf, 73728);
  gemm_bb<float><<<dim3(DIM / 128, 8192 / 128), 256, 0, stream>>>(
      attn_buf, w_proj_bf, b_proj, out, 8192, DIM, DIM);
}